// Round 2
// baseline (370.857 us; speedup 1.0000x reference)
//
#include <hip/hip_runtime.h>
#include <hip/hip_bf16.h>
#include <math.h>

// Problem: B=131072, D=512, C=5, K=10 experts.
// One GEMM [B,512] x [512,64pad] in bf16 MFMA + per-row softmax/relu epilogue.
// B matrix (64 KB packed bf16 fragments) staged in LDS once per block.
// v3: v2 (2 row-tiles/wave, depth-1 A-prefetch) + fix: epilogue stores of the
// 4 zero-padding columns (48+r, r>=12) are predicated off -- with stride 61
// they overflowed into the next row's gate columns (v2 correctness bug).
#define BATCH   131072
#define DIM     512
#define NCLS    5
#define NEXP    10
#define NW      60            // 10 gate cols + 50 expert cols
#define NCOL    64            // padded col count (4 MFMA col-tiles of 16)
#define PACK_TPB 256
#define TPB     512           // 8 waves/block
#define ROWS_PER_BLOCK 256    // 8 waves x 2 tiles x 16 rows
#define EPS_STRIDE 61         // odd stride: conflict-free epilogue row reads
                              // NOTE: < 64, so pad cols 60..63 must NOT be stored

typedef short bf16x8 __attribute__((ext_vector_type(8)));   // MFMA A/B frag (4 VGPRs)
typedef float f32x4  __attribute__((ext_vector_type(4)));   // MFMA C/D frag

// ---------------------------------------------------------------------------
// Pack weights into per-lane B-fragment order for mfma_f32_16x16x32_bf16:
// wfrag[((c*4 + t)*64 + lane)*8 + j] = B[k = 32c + (lane>>4)*8 + j][n = 16t + (lane&15)]
// n<10: gate col (Wg); 10<=n<60: expert (n-10)/5 class (n-10)%5 (We); else 0.
// bpack[64]: fp32 biases in the same n layout.
// ---------------------------------------------------------------------------
__global__ void pack_w_kernel(const float* __restrict__ We,
                              const float* __restrict__ be,
                              const float* __restrict__ Wg,
                              const float* __restrict__ bg,
                              unsigned short* __restrict__ wfrag,
                              float* __restrict__ bpack) {
    int idx = blockIdx.x * PACK_TPB + threadIdx.x;   // 0 .. 32767
    int c    = idx >> 11;                       // k-chunk 0..15
    int t    = (idx >> 9) & 3;                  // col tile 0..3
    int lane = (idx >> 3) & 63;
    int j    = idx & 7;
    int d = c * 32 + (lane >> 4) * 8 + j;       // 0..511
    int n = t * 16 + (lane & 15);               // 0..63
    float v = 0.0f;
    if (n < NEXP) {
        v = Wg[d * NEXP + n];
    } else if (n < NW) {
        int k  = (n - NEXP) / NCLS;
        int cc = (n - NEXP) % NCLS;
        v = We[(k * DIM + d) * NCLS + cc];
    }
    wfrag[idx] = __builtin_bit_cast(unsigned short, __float2bfloat16(v));
    if (idx < NCOL) {
        float bv = 0.0f;
        if (idx < NEXP) bv = bg[idx];
        else if (idx < NW) {
            int k  = (idx - NEXP) / NCLS;
            int cc = (idx - NEXP) % NCLS;
            bv = be[k * NCLS + cc];
        }
        bpack[idx] = bv;
    }
}

// Convert 8 fp32 (two float4) to a bf16x8 MFMA A-fragment.
#define CVT8(DST, VA, VB) do {                                               \
    float _v[8] = {(VA).x, (VA).y, (VA).z, (VA).w,                           \
                   (VB).x, (VB).y, (VB).z, (VB).w};                          \
    _Pragma("unroll")                                                        \
    for (int _j = 0; _j < 8; ++_j)                                           \
        (DST)[_j] = (short)__builtin_bit_cast(unsigned short,                \
                         __float2bfloat16(_v[_j]));                          \
} while (0)

// One K-step (32 k-values) for both row-tiles of this wave.
#define KSTEP(C, A0A, A0B, A1A, A1B) do {                                    \
    bf16x8 _b0 = bl[((C) * 4 + 0) * 64 + L];                                 \
    bf16x8 _b1 = bl[((C) * 4 + 1) * 64 + L];                                 \
    bf16x8 _b2 = bl[((C) * 4 + 2) * 64 + L];                                 \
    bf16x8 _b3 = bl[((C) * 4 + 3) * 64 + L];                                 \
    bf16x8 _af0, _af1;                                                       \
    CVT8(_af0, A0A, A0B);                                                    \
    CVT8(_af1, A1A, A1B);                                                    \
    acc0[0] = __builtin_amdgcn_mfma_f32_16x16x32_bf16(_af0, _b0, acc0[0], 0, 0, 0); \
    acc1[0] = __builtin_amdgcn_mfma_f32_16x16x32_bf16(_af1, _b0, acc1[0], 0, 0, 0); \
    acc0[1] = __builtin_amdgcn_mfma_f32_16x16x32_bf16(_af0, _b1, acc0[1], 0, 0, 0); \
    acc1[1] = __builtin_amdgcn_mfma_f32_16x16x32_bf16(_af1, _b1, acc1[1], 0, 0, 0); \
    acc0[2] = __builtin_amdgcn_mfma_f32_16x16x32_bf16(_af0, _b2, acc0[2], 0, 0, 0); \
    acc1[2] = __builtin_amdgcn_mfma_f32_16x16x32_bf16(_af1, _b2, acc1[2], 0, 0, 0); \
    acc0[3] = __builtin_amdgcn_mfma_f32_16x16x32_bf16(_af0, _b3, acc0[3], 0, 0, 0); \
    acc1[3] = __builtin_amdgcn_mfma_f32_16x16x32_bf16(_af1, _b3, acc1[3], 0, 0, 0); \
} while (0)

// ---------------------------------------------------------------------------
// Main kernel: 8 waves/block, each wave computes TWO 16-row x 64-col tiles
// (32 rows). A streamed from global with depth-1 register prefetch; B staged
// to LDS once (64 KB) and read via conflict-free ds_read_b128; no K-loop
// barrier. Epilogue reuses the B LDS region (B dead after K-loop).
// ---------------------------------------------------------------------------
__global__ __launch_bounds__(TPB, 4) void moe_mfma_kernel(
        const float* __restrict__ emb,
        const float4* __restrict__ wfrag4,
        const float* __restrict__ bpack,
        float* __restrict__ out) {
    __shared__ float4 smem4[4096];   // 64 KB: B fragments; reused as epilogue buf

    const int tid = threadIdx.x;
    const int w = tid >> 6;            // wave 0..7
    const int L = tid & 63;            // lane
    const int r = L & 15;              // A row within tile
    const int q = L >> 4;              // quad 0..3

    const size_t rowBase = (size_t)blockIdx.x * ROWS_PER_BLOCK + w * 32;
    const float* ap0 = emb + (rowBase + r) * DIM + q * 8;   // tile 0 rows
    const float* ap1 = ap0 + 16 * DIM;                      // tile 1 rows (+16)

    // Issue the first A loads BEFORE staging B: their ~900-cycle HBM latency
    // overlaps the 64 KB LDS stage + barrier.
    float4 n0a = *reinterpret_cast<const float4*>(ap0);
    float4 n0b = *reinterpret_cast<const float4*>(ap0 + 4);
    float4 n1a = *reinterpret_cast<const float4*>(ap1);
    float4 n1b = *reinterpret_cast<const float4*>(ap1 + 4);

    // ---- stage B: 64 KB, coalesced float4, once per block ----
    #pragma unroll
    for (int i = 0; i < 8; ++i)
        smem4[i * TPB + tid] = wfrag4[i * TPB + tid];
    __syncthreads();

    const bf16x8* bl = reinterpret_cast<const bf16x8*>(smem4);

    f32x4 acc0[4] = {{0.f,0.f,0.f,0.f},{0.f,0.f,0.f,0.f},
                     {0.f,0.f,0.f,0.f},{0.f,0.f,0.f,0.f}};
    f32x4 acc1[4] = {{0.f,0.f,0.f,0.f},{0.f,0.f,0.f,0.f},
                     {0.f,0.f,0.f,0.f},{0.f,0.f,0.f,0.f}};

    // K-loop: 16 steps of 32; prefetch step c+1 while computing step c.
    // Last step peeled so the prefetch never reads past the end of emb.
    #pragma unroll 5
    for (int c = 0; c < DIM / 32 - 1; ++c) {
        float4 a0a = n0a, a0b = n0b, a1a = n1a, a1b = n1b;
        const float* p0 = ap0 + (c + 1) * 32;
        const float* p1 = ap1 + (c + 1) * 32;
        n0a = *reinterpret_cast<const float4*>(p0);
        n0b = *reinterpret_cast<const float4*>(p0 + 4);
        n1a = *reinterpret_cast<const float4*>(p1);
        n1b = *reinterpret_cast<const float4*>(p1 + 4);
        KSTEP(c, a0a, a0b, a1a, a1b);
    }
    KSTEP(DIM / 32 - 1, n0a, n0b, n1a, n1b);

    // ---- epilogue: reuse B's LDS for the C transpose ----
    __syncthreads();                   // all waves done reading B
    float* eps = reinterpret_cast<float*>(smem4);   // 256 x 61 floats = 62.5 KB
    // C/D layout: col = lane&15, row = quad*4 + reg.
    // stride 61 (odd): row reads conflict-free; writes <=3-way bank alias.
    // Cols 60..63 of each MFMA tile are zero padding and are NEVER read by the
    // per-row pass (it consumes n < 60) -- they MUST NOT be stored, since with
    // stride 61 offsets 60..63 land in the next row's gate columns.
    #pragma unroll
    for (int i = 0; i < 4; ++i) {
        int rl0 = w * 32 + q * 4 + i;          // tile 0 row
        float* e0 = eps + rl0 * EPS_STRIDE + r;
        e0[ 0] = acc0[0][i];
        e0[16] = acc0[1][i];
        e0[32] = acc0[2][i];
        int rl1 = rl0 + 16;                    // tile 1 row
        float* e1 = eps + rl1 * EPS_STRIDE + r;
        e1[ 0] = acc1[0][i];
        e1[16] = acc1[1][i];
        e1[32] = acc1[2][i];
        if (r < 12) {                          // cols 48..59 only (skip padding)
            e0[48] = acc0[3][i];
            e1[48] = acc1[3][i];
        }
    }
    __syncthreads();

    // One thread per row: softmax(10) + relu + gate-weighted sum -> 5 outputs
    if (tid < ROWS_PER_BLOCK) {
        const float* row = eps + tid * EPS_STRIDE;
        float g[NEXP];
        float m = -INFINITY;
        #pragma unroll
        for (int k = 0; k < NEXP; ++k) {
            g[k] = row[k] + bpack[k];
            m = fmaxf(m, g[k]);
        }
        float s = 0.0f;
        #pragma unroll
        for (int k = 0; k < NEXP; ++k) {
            g[k] = __expf(g[k] - m);
            s += g[k];
        }
        float inv = 1.0f / s;

        float o[NCLS] = {0.f, 0.f, 0.f, 0.f, 0.f};
        #pragma unroll
        for (int k = 0; k < NEXP; ++k) {
            float gk = g[k] * inv;
            #pragma unroll
            for (int cc = 0; cc < NCLS; ++cc) {
                int n = NEXP + k * NCLS + cc;
                float e = row[n] + bpack[n];
                e = fmaxf(e, 0.0f);
                o[cc] = fmaf(gk, e, o[cc]);
            }
        }
        size_t ob = ((size_t)blockIdx.x * ROWS_PER_BLOCK + tid) * NCLS;
        #pragma unroll
        for (int cc = 0; cc < NCLS; ++cc) out[ob + cc] = o[cc];
    }
}

extern "C" void kernel_launch(void* const* d_in, const int* in_sizes, int n_in,
                              void* d_out, int out_size, void* d_ws, size_t ws_size,
                              hipStream_t stream) {
    const float* emb = (const float*)d_in[0];   // [B, D]
    const float* We  = (const float*)d_in[1];   // [K, D, C]
    const float* be  = (const float*)d_in[2];   // [K, C]
    const float* Wg  = (const float*)d_in[3];   // [D, K]
    const float* bg  = (const float*)d_in[4];   // [K]
    float* out = (float*)d_out;                 // [B, C]

    unsigned short* wfrag = (unsigned short*)d_ws;            // 32768 ushort = 64 KB
    float* bpack = (float*)((char*)d_ws + 32768 * sizeof(unsigned short));

    pack_w_kernel<<<(16 * 4 * 64 * 8) / PACK_TPB, PACK_TPB, 0, stream>>>(
        We, be, Wg, bg, wfrag, bpack);
    moe_mfma_kernel<<<BATCH / ROWS_PER_BLOCK, TPB, 0, stream>>>(
        emb, (const float4*)wfrag, bpack, out);
}